// Round 5
// baseline (340.878 us; speedup 1.0000x reference)
//
#include <hip/hip_runtime.h>
#include <cstdint>
#include <cstddef>

#define B 4
#define N 16
#define V 32
#define HW 25600
#define TOPK 7
#define NSL 25      // kTop slabs of 1024 px
#define NCA 200     // kA chunks of 128 px
#define NCC 400     // kC chunks of 64 px

__device__ __forceinline__ bool better(float av, int ai, float bv, int bi) {
    return (av > bv) || (av == bv && ai < bi);
}

// ---------------- kTop: per-(bn, 1024px slab) top-7 candidates + cnt ----------------
__global__ __launch_bounds__(256, 4) void kTop(
    const float* __restrict__ pred, const float* __restrict__ gt,
    float* __restrict__ cand_val, int* __restrict__ cand_idx,
    float* __restrict__ cntbuf) {
    int s = blockIdx.x;            // 64*25
    int bn = s / NSL, sl = s % NSL;
    int b = bn >> 4;
    int tid = threadIdx.x;
    int lane = tid & 63, wave = tid >> 6;
    int p0 = sl * 1024 + tid * 4;

    float4 g4 = *reinterpret_cast<const float4*>(gt + (size_t)bn * HW + p0);
    float4 p4 = *reinterpret_cast<const float4*>(pred + (size_t)b * HW + p0);

    float cnt = g4.x + g4.y + g4.z + g4.w;
#pragma unroll
    for (int off = 32; off > 0; off >>= 1) cnt += __shfl_down(cnt, off);
    if (lane == 0) atomicAdd(cntbuf + bn, cnt);

    float cva[4] = { p4.x * g4.x, p4.y * g4.y, p4.z * g4.z, p4.w * g4.w };
    int cia[4] = { p0, p0 + 1, p0 + 2, p0 + 3 };

    __shared__ float rwv[4];
    __shared__ int rwi[4];
    int cbase = (bn * NSL + sl) * TOPK;
    for (int r = 0; r < TOPK; ++r) {
        float bv = cva[0]; int bi = cia[0];
#pragma unroll
        for (int j = 1; j < 4; ++j)
            if (better(cva[j], cia[j], bv, bi)) { bv = cva[j]; bi = cia[j]; }
#pragma unroll
        for (int m = 1; m <= 32; m <<= 1) {
            float ov = __shfl_xor(bv, m);
            int oi = __shfl_xor(bi, m);
            if (better(ov, oi, bv, bi)) { bv = ov; bi = oi; }
        }
        if (lane == 0) { rwv[wave] = bv; rwi[wave] = bi; }
        __syncthreads();
        float fv = rwv[0]; int fi = rwi[0];
#pragma unroll
        for (int w = 1; w < 4; ++w)
            if (better(rwv[w], rwi[w], fv, fi)) { fv = rwv[w]; fi = rwi[w]; }
#pragma unroll
        for (int j = 0; j < 4; ++j)
            if (cia[j] == fi) { cva[j] = -INFINITY; cia[j] = 0x7fffffff; }
        if (tid == 0) { cand_val[cbase + r] = fv; cand_idx[cbase + r] = fi; }
        __syncthreads();
    }
}

// ---------------- kA: ms[n][v] partials per (b, 128px chunk) ----------------
// thread = (ng4 wave x vg8 x pg8): 4n x 4v register tile, 16 px.
__global__ __launch_bounds__(256, 4) void kA(
    const float* __restrict__ feat, const float* __restrict__ gt,
    float* __restrict__ ms_part) {
    int s = blockIdx.x;                 // 800
    int xcd = s & 7;
    int b = xcd >> 1;                   // pin b to XCD pair for L2 locality
    int ch = (s >> 3) * 2 + (xcd & 1);  // 0..199
    int c0 = ch * 128;
    int tid = threadIdx.x;
    int ng = tid >> 6, vg = (tid >> 3) & 7, pg = tid & 7;

    const float* gb = gt + (size_t)(b * N + ng * 4) * HW + c0 + pg * 4;
    const float* fb = feat + (size_t)(b * V + vg * 4) * HW + c0 + pg * 4;

    float acc[4][4];
#pragma unroll
    for (int i = 0; i < 4; ++i)
#pragma unroll
        for (int j = 0; j < 4; ++j) acc[i][j] = 0.f;

#pragma unroll
    for (int q = 0; q < 4; ++q) {
        int p = q * 32;
        float4 g4[4], f4[4];
#pragma unroll
        for (int i = 0; i < 4; ++i)
            g4[i] = *reinterpret_cast<const float4*>(gb + (size_t)i * HW + p);
#pragma unroll
        for (int j = 0; j < 4; ++j)
            f4[j] = *reinterpret_cast<const float4*>(fb + (size_t)j * HW + p);
#pragma unroll
        for (int i = 0; i < 4; ++i)
#pragma unroll
            for (int j = 0; j < 4; ++j) {
                acc[i][j] = fmaf(g4[i].x, f4[j].x, acc[i][j]);
                acc[i][j] = fmaf(g4[i].y, f4[j].y, acc[i][j]);
                acc[i][j] = fmaf(g4[i].z, f4[j].z, acc[i][j]);
                acc[i][j] = fmaf(g4[i].w, f4[j].w, acc[i][j]);
            }
    }
#pragma unroll
    for (int m = 1; m <= 4; m <<= 1)
#pragma unroll
        for (int i = 0; i < 4; ++i)
#pragma unroll
            for (int j = 0; j < 4; ++j) acc[i][j] += __shfl_xor(acc[i][j], m);
    if (pg == 0) {
        float* dst = ms_part + (size_t)(b * NCA + ch) * 512;
#pragma unroll
        for (int i = 0; i < 4; ++i)
#pragma unroll
            for (int j = 0; j < 4; ++j)
                dst[(ng * 4 + i) * 32 + vg * 4 + j] = acc[i][j];
    }
}

// ---------------- kB: merge candidates, finalize mu, build E ----------------
__global__ __launch_bounds__(256) void kB(
    const float* __restrict__ feat, const float* __restrict__ ms_part,
    const float* __restrict__ cand_val, const int* __restrict__ cand_idx,
    const float* __restrict__ cntbuf,
    float* __restrict__ Ebuf, float* __restrict__ musqbuf) {
    int bn = blockIdx.x;
    int b = bn >> 4, n = bn & 15;
    int tid = threadIdx.x;
    int lane = tid & 63, wave = tid >> 6;

    __shared__ int idx7[TOPK];
    __shared__ float msred[2][32];

    if (wave == 0) {
        // merge 175 candidates: lane holds up to 3
        float cv0 = -INFINITY, cv1 = -INFINITY, cv2 = -INFINITY;
        int ci0 = 0x7fffffff, ci1 = 0x7fffffff, ci2 = 0x7fffffff;
        const float* cvp = cand_val + (size_t)bn * NSL * TOPK;
        const int* cip = cand_idx + (size_t)bn * NSL * TOPK;
        int t0 = lane, t1 = lane + 64, t2 = lane + 128;
        if (t0 < NSL * TOPK) { cv0 = cvp[t0]; ci0 = cip[t0]; }
        if (t1 < NSL * TOPK) { cv1 = cvp[t1]; ci1 = cip[t1]; }
        if (t2 < NSL * TOPK) { cv2 = cvp[t2]; ci2 = cip[t2]; }
#pragma unroll
        for (int r = 0; r < TOPK; ++r) {
            float bv = cv0; int bi = ci0;
            if (better(cv1, ci1, bv, bi)) { bv = cv1; bi = ci1; }
            if (better(cv2, ci2, bv, bi)) { bv = cv2; bi = ci2; }
#pragma unroll
            for (int m = 1; m <= 32; m <<= 1) {
                float ov = __shfl_xor(bv, m);
                int oi = __shfl_xor(bi, m);
                if (better(ov, oi, bv, bi)) { bv = ov; bi = oi; }
            }
            if (ci0 == bi) { cv0 = -INFINITY; ci0 = 0x7fffffff; }
            if (ci1 == bi) { cv1 = -INFINITY; ci1 = 0x7fffffff; }
            if (ci2 == bi) { cv2 = -INFINITY; ci2 = 0x7fffffff; }
            if (lane == 0) idx7[r] = bi;
        }
    } else if (wave <= 2) {
        int half = wave - 1;
        int v = lane & 31, hh = lane >> 5;
        int cstart = half * 100 + hh * 50;
        const float* src = ms_part + (size_t)b * NCA * 512 + n * 32 + v;
        float sm = 0.f;
        for (int k = 0; k < 50; ++k) sm += src[(size_t)(cstart + k) * 512];
        sm += __shfl_xor(sm, 32);
        if (lane < 32) msred[half][v] = sm;
    }
    __syncthreads();

    if (tid < 32) {
        float msum = msred[0][tid] + msred[1][tid];
        float cnt = cntbuf[bn];
        float pix = fmaxf(cnt, 1.0f);
        float mu = msum / pix;
        Ebuf[(size_t)bn * 256 + tid] = mu;
        float msq = mu * mu;
#pragma unroll
        for (int m = 1; m <= 16; m <<= 1) msq += __shfl_xor(msq, m);
        if (tid == 0) musqbuf[bn] = msq;
    } else {
        int t = tid - 32;
        if (t < 224) {
            int r = t >> 5, v = t & 31;
            Ebuf[(size_t)bn * 256 + (r + 1) * 32 + v] =
                feat[((size_t)b * V + v) * HW + idx7[r]];
        }
    }
}

// ---------------- kC: sigmoid-GEMM dice partials per (b, 64px chunk) ----------------
// thread = (n16 x pg16): 8 rows x 4 px tile; coalesced block-partial output.
__global__ __launch_bounds__(256, 4) void kC(
    const float* __restrict__ feat, const float* __restrict__ gt,
    const float* __restrict__ Ebuf,
    float* __restrict__ sums_part, float* __restrict__ s2buf) {
    int s = blockIdx.x;                 // 1600
    int xcd = s & 7;
    int b = xcd >> 1;
    int ch = (s >> 3) * 2 + (xcd & 1);  // 0..399
    int c0 = ch * 64;
    int tid = threadIdx.x;
    int n = tid >> 4, pg = tid & 15;

    __shared__ float e_lds[8 * 16 * 36];
    __shared__ float red[16][17];

    const float* eb = Ebuf + (size_t)b * 4096;
#pragma unroll
    for (int k = 0; k < 16; ++k) {
        int q = tid + 256 * k;
        int nn = q >> 8, rr = (q >> 5) & 7, vv = q & 31;
        e_lds[(rr * 16 + nn) * 36 + vv] = eb[q];
    }
    __syncthreads();

    const float* fb = feat + (size_t)b * V * HW + c0 + pg * 4;
    float4 g4 = *reinterpret_cast<const float4*>(gt + (size_t)(b * N + n) * HW + c0 + pg * 4);

    float acc[8][4];
#pragma unroll
    for (int r = 0; r < 8; ++r)
#pragma unroll
        for (int j = 0; j < 4; ++j) acc[r][j] = 0.f;
    float ff0 = 0.f, ff1 = 0.f, ff2 = 0.f, ff3 = 0.f;

#pragma unroll
    for (int vq = 0; vq < 8; ++vq) {
        float4 f4[4];
#pragma unroll
        for (int j = 0; j < 4; ++j)
            f4[j] = *reinterpret_cast<const float4*>(fb + (size_t)(vq * 4 + j) * HW);
#pragma unroll
        for (int j = 0; j < 4; ++j) {
            ff0 = fmaf(f4[j].x, f4[j].x, ff0);
            ff1 = fmaf(f4[j].y, f4[j].y, ff1);
            ff2 = fmaf(f4[j].z, f4[j].z, ff2);
            ff3 = fmaf(f4[j].w, f4[j].w, ff3);
        }
#pragma unroll
        for (int r = 0; r < 8; ++r) {
            float4 e4 = *reinterpret_cast<const float4*>(&e_lds[(r * 16 + n) * 36 + vq * 4]);
            acc[r][0] = fmaf(e4.x, f4[0].x, acc[r][0]);
            acc[r][0] = fmaf(e4.y, f4[1].x, acc[r][0]);
            acc[r][0] = fmaf(e4.z, f4[2].x, acc[r][0]);
            acc[r][0] = fmaf(e4.w, f4[3].x, acc[r][0]);
            acc[r][1] = fmaf(e4.x, f4[0].y, acc[r][1]);
            acc[r][1] = fmaf(e4.y, f4[1].y, acc[r][1]);
            acc[r][1] = fmaf(e4.z, f4[2].y, acc[r][1]);
            acc[r][1] = fmaf(e4.w, f4[3].y, acc[r][1]);
            acc[r][2] = fmaf(e4.x, f4[0].z, acc[r][2]);
            acc[r][2] = fmaf(e4.y, f4[1].z, acc[r][2]);
            acc[r][2] = fmaf(e4.z, f4[2].z, acc[r][2]);
            acc[r][2] = fmaf(e4.w, f4[3].z, acc[r][2]);
            acc[r][3] = fmaf(e4.x, f4[0].w, acc[r][3]);
            acc[r][3] = fmaf(e4.y, f4[1].w, acc[r][3]);
            acc[r][3] = fmaf(e4.z, f4[2].w, acc[r][3]);
            acc[r][3] = fmaf(e4.w, f4[3].w, acc[r][3]);
        }
    }

    // embedding-l2 numerator: s2 = sum_p gt * (sum_v f^2)
    float s2c = g4.x * ff0 + g4.y * ff1 + g4.z * ff2 + g4.w * ff3;
#pragma unroll
    for (int m = 1; m <= 8; m <<= 1) s2c += __shfl_xor(s2c, m);
    if (pg == 0) atomicAdd(s2buf + b * N + n, s2c);

    float p2[8], tp[8];
#pragma unroll
    for (int r = 0; r < 8; ++r) { p2[r] = 0.f; tp[r] = 0.f; }
    float ga[4] = { g4.x, g4.y, g4.z, g4.w };
#pragma unroll
    for (int r = 0; r < 8; ++r)
#pragma unroll
        for (int j = 0; j < 4; ++j) {
            float sg = 1.f / (1.f + __expf(-acc[r][j]));
            p2[r] = fmaf(sg, sg, p2[r]);
            tp[r] = fmaf(ga[j], sg, tp[r]);
        }
#pragma unroll
    for (int m = 1; m <= 8; m <<= 1)
#pragma unroll
        for (int r = 0; r < 8; ++r) {
            p2[r] += __shfl_xor(p2[r], m);
            tp[r] += __shfl_xor(tp[r], m);
        }
    if (pg == 0) {
#pragma unroll
        for (int r = 0; r < 8; ++r) {
            red[n][r * 2] = p2[r];
            red[n][r * 2 + 1] = tp[r];
        }
    }
    __syncthreads();
    sums_part[(size_t)(b * NCC + ch) * 256 + tid] = red[tid >> 4][tid & 15];
}

// ---------------- kD: reduce dice partials, fold all three losses ----------------
__global__ __launch_bounds__(256) void kD(
    const float* __restrict__ sums_part, const float* __restrict__ cntbuf,
    const float* __restrict__ s2buf, const float* __restrict__ musqbuf,
    const int* __restrict__ valid, float* __restrict__ out) {
    int bn = blockIdx.x;       // 64
    int b = bn >> 4, n = bn & 15;
    int tid = threadIdx.x;
    int slot = tid & 15, cg = tid >> 4;
    int lane = tid & 63, wave = tid >> 6;

    __shared__ float red2[4][17];
    __shared__ float fin[16];

    float sv = 0.f;
    const float* src = sums_part + (size_t)b * NCC * 256 + n * 16 + slot;
    for (int k = 0; k < 25; ++k) sv += src[(size_t)(cg + 16 * k) * 256];
    sv += __shfl_xor(sv, 16);
    sv += __shfl_xor(sv, 32);
    if (lane < 16) red2[wave][lane] = sv;
    __syncthreads();
    if (tid < 16) fin[tid] = red2[0][tid] + red2[1][tid] + red2[2][tid] + red2[3][tid];
    __syncthreads();

    if (tid == 0) {
        float vw = (float)valid[bn];
        float cnt = cntbuf[bn];
        float pix = fmaxf(cnt, 1.0f);
        float mloss = 0.f, iloss = 0.f;
#pragma unroll
        for (int r = 0; r < 8; ++r) {
            float p2 = fin[r * 2];
            float tp = fin[r * 2 + 1];
            float denom = fmaxf(p2 + cnt, 1e-8f);
            float dice = 1.f - 2.f * tp / denom;
            if (r == 0) mloss = dice * vw;
            else iloss += dice * vw;
        }
        float l2 = (s2buf[bn] / pix - musqbuf[bn]) * vw;
        atomicAdd(out + 0, mloss);
        atomicAdd(out + 1, iloss);
        atomicAdd(out + 2, l2);
    }
}

extern "C" void kernel_launch(void* const* d_in, const int* in_sizes, int n_in,
                              void* d_out, int out_size, void* d_ws, size_t ws_size,
                              hipStream_t stream) {
    const float* pred = (const float*)d_in[0];
    const float* feat = (const float*)d_in[1];
    const float* gtin = (const float*)d_in[2];
    const int* valid  = (const int*)d_in[3];
    float* out = (float*)d_out;

    char* ws = (char*)d_ws;
    float* ms_part   = (float*)(ws);                 // 800*512*4   = 1,638,400
    float* cand_val  = (float*)(ws + 1638400);       // 64*175*4    =    44,800
    int*   cand_idx  = (int*)  (ws + 1683200);       //                  44,800
    float* sums_part = (float*)(ws + 1728000);       // 1600*256*4  = 1,638,400
    float* Ebuf      = (float*)(ws + 3366400);       // 64*256*4    =    65,536
    float* cntbuf    = (float*)(ws + 3431936);       // 256
    float* s2buf     = (float*)(ws + 3432192);       // 256
    float* musqbuf   = (float*)(ws + 3432448);       // 256

    hipMemsetAsync(out, 0, 3 * sizeof(float), stream);
    hipMemsetAsync(ws + 3431936, 0, 512, stream);    // cntbuf + s2buf

    kTop<<<B * N * NSL, 256, 0, stream>>>(pred, gtin, cand_val, cand_idx, cntbuf);
    kA<<<B * NCA, 256, 0, stream>>>(feat, gtin, ms_part);
    kB<<<B * N, 256, 0, stream>>>(feat, ms_part, cand_val, cand_idx, cntbuf,
                                  Ebuf, musqbuf);
    kC<<<B * NCC, 256, 0, stream>>>(feat, gtin, Ebuf, sums_part, s2buf);
    kD<<<B * N, 256, 0, stream>>>(sums_part, cntbuf, s2buf, musqbuf, valid, out);
}

// Round 6
// 104.329 us; speedup vs baseline: 3.2673x; 3.2673x over previous
//
#include <hip/hip_runtime.h>
#include <cstdint>
#include <cstddef>

#define B 4
#define N 16
#define V 32
#define HW 25600
#define TOPK 7
#define NSL 25      // kTop slabs of 1024 px
#define NCA 200     // kA chunks of 128 px
#define NCC 400     // kC chunks of 64 px

__device__ __forceinline__ bool better(float av, int ai, float bv, int bi) {
    return (av > bv) || (av == bv && ai < bi);
}

// ---------------- kTop: per-(bn, 1024px slab) top-7 candidates + cnt ----------------
__global__ __launch_bounds__(256) void kTop(
    const float* __restrict__ pred, const float* __restrict__ gt,
    float* __restrict__ cand_val, int* __restrict__ cand_idx,
    float* __restrict__ cntbuf) {
    int s = blockIdx.x;            // 64*25
    int bn = s / NSL, sl = s % NSL;
    int b = bn >> 4;
    int tid = threadIdx.x;
    int lane = tid & 63, wave = tid >> 6;
    int p0 = sl * 1024 + tid * 4;

    float4 g4 = *reinterpret_cast<const float4*>(gt + (size_t)bn * HW + p0);
    float4 p4 = *reinterpret_cast<const float4*>(pred + (size_t)b * HW + p0);

    float cnt = g4.x + g4.y + g4.z + g4.w;
#pragma unroll
    for (int off = 32; off > 0; off >>= 1) cnt += __shfl_down(cnt, off);
    if (lane == 0) atomicAdd(cntbuf + bn, cnt);

    float cva[4] = { p4.x * g4.x, p4.y * g4.y, p4.z * g4.z, p4.w * g4.w };
    int cia[4] = { p0, p0 + 1, p0 + 2, p0 + 3 };

    __shared__ float rwv[4];
    __shared__ int rwi[4];
    int cbase = (bn * NSL + sl) * TOPK;
    for (int r = 0; r < TOPK; ++r) {
        float bv = cva[0]; int bi = cia[0];
#pragma unroll
        for (int j = 1; j < 4; ++j)
            if (better(cva[j], cia[j], bv, bi)) { bv = cva[j]; bi = cia[j]; }
#pragma unroll
        for (int m = 1; m <= 32; m <<= 1) {
            float ov = __shfl_xor(bv, m);
            int oi = __shfl_xor(bi, m);
            if (better(ov, oi, bv, bi)) { bv = ov; bi = oi; }
        }
        if (lane == 0) { rwv[wave] = bv; rwi[wave] = bi; }
        __syncthreads();
        float fv = rwv[0]; int fi = rwi[0];
#pragma unroll
        for (int w = 1; w < 4; ++w)
            if (better(rwv[w], rwi[w], fv, fi)) { fv = rwv[w]; fi = rwi[w]; }
#pragma unroll
        for (int j = 0; j < 4; ++j)
            if (cia[j] == fi) { cva[j] = -INFINITY; cia[j] = 0x7fffffff; }
        if (tid == 0) { cand_val[cbase + r] = fv; cand_idx[cbase + r] = fi; }
        __syncthreads();
    }
}

// ---------------- kA: ms[n][v] + s2[n] partials per (b, 128px chunk) ----------------
// thread = (ng4 wave x vg8 x pg8): 4n x 4v register tile, 16 px each.
__global__ __launch_bounds__(256) void kA(
    const float* __restrict__ feat, const float* __restrict__ gt,
    float* __restrict__ ms_part, float* __restrict__ s2_part) {
    int s = blockIdx.x;                 // 800
    int xcd = s & 7;
    int b = xcd >> 1;                   // pin b to XCD pair for L2 locality
    int ch = (s >> 3) * 2 + (xcd & 1);  // 0..199
    int c0 = ch * 128;
    int tid = threadIdx.x;
    int ng = tid >> 6, vg = (tid >> 3) & 7, pg = tid & 7;

    const float* gb = gt + (size_t)(b * N + ng * 4) * HW + c0 + pg * 4;
    const float* fb = feat + (size_t)(b * V + vg * 4) * HW + c0 + pg * 4;

    float acc[4][4];
#pragma unroll
    for (int i = 0; i < 4; ++i)
#pragma unroll
        for (int j = 0; j < 4; ++j) acc[i][j] = 0.f;
    float s2a[4] = { 0.f, 0.f, 0.f, 0.f };

#pragma unroll
    for (int q = 0; q < 4; ++q) {
        int p = q * 32;
        float4 g4[4], f4[4];
#pragma unroll
        for (int i = 0; i < 4; ++i)
            g4[i] = *reinterpret_cast<const float4*>(gb + (size_t)i * HW + p);
#pragma unroll
        for (int j = 0; j < 4; ++j)
            f4[j] = *reinterpret_cast<const float4*>(fb + (size_t)j * HW + p);
        float ffx = 0.f, ffy = 0.f, ffz = 0.f, ffw = 0.f;
#pragma unroll
        for (int j = 0; j < 4; ++j) {
            ffx = fmaf(f4[j].x, f4[j].x, ffx);
            ffy = fmaf(f4[j].y, f4[j].y, ffy);
            ffz = fmaf(f4[j].z, f4[j].z, ffz);
            ffw = fmaf(f4[j].w, f4[j].w, ffw);
        }
#pragma unroll
        for (int i = 0; i < 4; ++i) {
#pragma unroll
            for (int j = 0; j < 4; ++j) {
                acc[i][j] = fmaf(g4[i].x, f4[j].x, acc[i][j]);
                acc[i][j] = fmaf(g4[i].y, f4[j].y, acc[i][j]);
                acc[i][j] = fmaf(g4[i].z, f4[j].z, acc[i][j]);
                acc[i][j] = fmaf(g4[i].w, f4[j].w, acc[i][j]);
            }
            s2a[i] = fmaf(g4[i].x, ffx, s2a[i]);
            s2a[i] = fmaf(g4[i].y, ffy, s2a[i]);
            s2a[i] = fmaf(g4[i].z, ffz, s2a[i]);
            s2a[i] = fmaf(g4[i].w, ffw, s2a[i]);
        }
    }
    // ms: reduce over pg (lane bits 0..2)
#pragma unroll
    for (int m = 1; m <= 4; m <<= 1)
#pragma unroll
        for (int i = 0; i < 4; ++i)
#pragma unroll
            for (int j = 0; j < 4; ++j) acc[i][j] += __shfl_xor(acc[i][j], m);
    size_t blk = (size_t)(b * NCA + ch);
    if (pg == 0) {
        float* dst = ms_part + blk * 512;
#pragma unroll
        for (int i = 0; i < 4; ++i)
#pragma unroll
            for (int j = 0; j < 4; ++j)
                dst[(ng * 4 + i) * 32 + vg * 4 + j] = acc[i][j];
    }
    // s2: reduce over (vg,pg) = lane bits 0..5
#pragma unroll
    for (int m = 1; m <= 32; m <<= 1)
#pragma unroll
        for (int i = 0; i < 4; ++i) s2a[i] += __shfl_xor(s2a[i], m);
    if ((tid & 63) == 0) {
#pragma unroll
        for (int i = 0; i < 4; ++i)
            s2_part[blk * 16 + ng * 4 + i] = s2a[i];
    }
}

// ---------------- kB: merge candidates, finalize mu, build E, emit l2 loss ----------------
__global__ __launch_bounds__(256) void kB(
    const float* __restrict__ feat, const float* __restrict__ ms_part,
    const float* __restrict__ s2_part,
    const float* __restrict__ cand_val, const int* __restrict__ cand_idx,
    const float* __restrict__ cntbuf, const int* __restrict__ valid,
    float* __restrict__ Ebuf, float* __restrict__ out) {
    int bn = blockIdx.x;
    int b = bn >> 4, n = bn & 15;
    int tid = threadIdx.x;
    int lane = tid & 63, wave = tid >> 6;

    __shared__ int idx7[TOPK];
    __shared__ float msred[2][32];
    __shared__ float s2sh;

    if (wave == 0) {
        // merge 175 candidates: lane holds up to 3
        float cv0 = -INFINITY, cv1 = -INFINITY, cv2 = -INFINITY;
        int ci0 = 0x7fffffff, ci1 = 0x7fffffff, ci2 = 0x7fffffff;
        const float* cvp = cand_val + (size_t)bn * NSL * TOPK;
        const int* cip = cand_idx + (size_t)bn * NSL * TOPK;
        int t0 = lane, t1 = lane + 64, t2 = lane + 128;
        if (t0 < NSL * TOPK) { cv0 = cvp[t0]; ci0 = cip[t0]; }
        if (t1 < NSL * TOPK) { cv1 = cvp[t1]; ci1 = cip[t1]; }
        if (t2 < NSL * TOPK) { cv2 = cvp[t2]; ci2 = cip[t2]; }
#pragma unroll
        for (int r = 0; r < TOPK; ++r) {
            float bv = cv0; int bi = ci0;
            if (better(cv1, ci1, bv, bi)) { bv = cv1; bi = ci1; }
            if (better(cv2, ci2, bv, bi)) { bv = cv2; bi = ci2; }
#pragma unroll
            for (int m = 1; m <= 32; m <<= 1) {
                float ov = __shfl_xor(bv, m);
                int oi = __shfl_xor(bi, m);
                if (better(ov, oi, bv, bi)) { bv = ov; bi = oi; }
            }
            if (ci0 == bi) { cv0 = -INFINITY; ci0 = 0x7fffffff; }
            if (ci1 == bi) { cv1 = -INFINITY; ci1 = 0x7fffffff; }
            if (ci2 == bi) { cv2 = -INFINITY; ci2 = 0x7fffffff; }
            if (lane == 0) idx7[r] = bi;
        }
    } else if (wave <= 2) {
        int half = wave - 1;
        int v = lane & 31, hh = lane >> 5;
        int cstart = half * 100 + hh * 50;
        const float* src = ms_part + (size_t)b * NCA * 512 + n * 32 + v;
        float sm = 0.f;
        for (int k = 0; k < 50; ++k) sm += src[(size_t)(cstart + k) * 512];
        sm += __shfl_xor(sm, 32);
        if (lane < 32) msred[half][v] = sm;
    } else {
        // wave 3: reduce s2 over 200 chunks
        float sv = 0.f;
        const float* src = s2_part + (size_t)b * NCA * 16 + n;
        for (int k = lane; k < NCA; k += 64) sv += src[(size_t)k * 16];
#pragma unroll
        for (int m = 1; m <= 32; m <<= 1) sv += __shfl_xor(sv, m);
        if (lane == 0) s2sh = sv;
    }
    __syncthreads();

    if (tid < 32) {
        float msum = msred[0][tid] + msred[1][tid];
        float cnt = cntbuf[bn];
        float pix = fmaxf(cnt, 1.0f);
        float mu = msum / pix;
        Ebuf[(size_t)bn * 256 + tid] = mu;
        float msq = mu * mu;
#pragma unroll
        for (int m = 1; m <= 16; m <<= 1) msq += __shfl_xor(msq, m);
        if (tid == 0) {
            float l2 = (s2sh / pix - msq) * (float)valid[bn];
            atomicAdd(out + 2, l2);
        }
    } else {
        int t = tid - 32;
        if (t < 224) {
            int r = t >> 5, v = t & 31;
            Ebuf[(size_t)bn * 256 + (r + 1) * 32 + v] =
                feat[((size_t)b * V + v) * HW + idx7[r]];
        }
    }
}

// ---------------- kC: sigmoid-GEMM dice partials per (b, 64px chunk) ----------------
// thread = (n16 x pg16): 8 rows x 4 px tile, double-buffered feat prefetch.
__global__ __launch_bounds__(256) void kC(
    const float* __restrict__ feat, const float* __restrict__ gt,
    const float* __restrict__ Ebuf, float* __restrict__ sums_part) {
    int s = blockIdx.x;                 // 1600
    int xcd = s & 7;
    int b = xcd >> 1;
    int ch = (s >> 3) * 2 + (xcd & 1);  // 0..399
    int c0 = ch * 64;
    int tid = threadIdx.x;
    int n = tid >> 4, pg = tid & 15;

    __shared__ float e_lds[8 * 16 * 36];
    __shared__ float red[16][17];

    const float* eb = Ebuf + (size_t)b * 4096;
#pragma unroll
    for (int k = 0; k < 16; ++k) {
        int q = tid + 256 * k;
        int nn = q >> 8, rr = (q >> 5) & 7, vv = q & 31;
        e_lds[(rr * 16 + nn) * 36 + vv] = eb[q];
    }
    __syncthreads();

    const float* fb = feat + (size_t)b * V * HW + c0 + pg * 4;
    float4 g4 = *reinterpret_cast<const float4*>(gt + (size_t)(b * N + n) * HW + c0 + pg * 4);

    float acc[8][4];
#pragma unroll
    for (int r = 0; r < 8; ++r)
#pragma unroll
        for (int j = 0; j < 4; ++j) acc[r][j] = 0.f;

    // double-buffered v-quad loop: prefetch vq+1 while computing vq
    float4 c0_ = *reinterpret_cast<const float4*>(fb);
    float4 c1_ = *reinterpret_cast<const float4*>(fb + HW);
    float4 c2_ = *reinterpret_cast<const float4*>(fb + 2 * (size_t)HW);
    float4 c3_ = *reinterpret_cast<const float4*>(fb + 3 * (size_t)HW);
#pragma unroll
    for (int vq = 0; vq < 8; ++vq) {
        float4 n0_, n1_, n2_, n3_;
        if (vq < 7) {
            const float* np = fb + (size_t)(vq * 4 + 4) * HW;
            n0_ = *reinterpret_cast<const float4*>(np);
            n1_ = *reinterpret_cast<const float4*>(np + HW);
            n2_ = *reinterpret_cast<const float4*>(np + 2 * (size_t)HW);
            n3_ = *reinterpret_cast<const float4*>(np + 3 * (size_t)HW);
        }
#pragma unroll
        for (int r = 0; r < 8; ++r) {
            float4 e4 = *reinterpret_cast<const float4*>(&e_lds[(r * 16 + n) * 36 + vq * 4]);
            acc[r][0] = fmaf(e4.x, c0_.x, acc[r][0]);
            acc[r][0] = fmaf(e4.y, c1_.x, acc[r][0]);
            acc[r][0] = fmaf(e4.z, c2_.x, acc[r][0]);
            acc[r][0] = fmaf(e4.w, c3_.x, acc[r][0]);
            acc[r][1] = fmaf(e4.x, c0_.y, acc[r][1]);
            acc[r][1] = fmaf(e4.y, c1_.y, acc[r][1]);
            acc[r][1] = fmaf(e4.z, c2_.y, acc[r][1]);
            acc[r][1] = fmaf(e4.w, c3_.y, acc[r][1]);
            acc[r][2] = fmaf(e4.x, c0_.z, acc[r][2]);
            acc[r][2] = fmaf(e4.y, c1_.z, acc[r][2]);
            acc[r][2] = fmaf(e4.z, c2_.z, acc[r][2]);
            acc[r][2] = fmaf(e4.w, c3_.z, acc[r][2]);
            acc[r][3] = fmaf(e4.x, c0_.w, acc[r][3]);
            acc[r][3] = fmaf(e4.y, c1_.w, acc[r][3]);
            acc[r][3] = fmaf(e4.z, c2_.w, acc[r][3]);
            acc[r][3] = fmaf(e4.w, c3_.w, acc[r][3]);
        }
        if (vq < 7) { c0_ = n0_; c1_ = n1_; c2_ = n2_; c3_ = n3_; }
    }

    float p2[8], tp[8];
#pragma unroll
    for (int r = 0; r < 8; ++r) { p2[r] = 0.f; tp[r] = 0.f; }
    float ga[4] = { g4.x, g4.y, g4.z, g4.w };
#pragma unroll
    for (int r = 0; r < 8; ++r)
#pragma unroll
        for (int j = 0; j < 4; ++j) {
            float sg = 1.f / (1.f + __expf(-acc[r][j]));
            p2[r] = fmaf(sg, sg, p2[r]);
            tp[r] = fmaf(ga[j], sg, tp[r]);
        }
    // reduce over pg (lane bits 0..3)
#pragma unroll
    for (int m = 1; m <= 8; m <<= 1)
#pragma unroll
        for (int r = 0; r < 8; ++r) {
            p2[r] += __shfl_xor(p2[r], m);
            tp[r] += __shfl_xor(tp[r], m);
        }
    if (pg == 0) {
#pragma unroll
        for (int r = 0; r < 8; ++r) {
            red[n][r * 2] = p2[r];
            red[n][r * 2 + 1] = tp[r];
        }
    }
    __syncthreads();
    sums_part[(size_t)(b * NCC + ch) * 256 + tid] = red[tid >> 4][tid & 15];
}

// ---------------- kD: reduce dice partials, fold dice losses ----------------
__global__ __launch_bounds__(256) void kD(
    const float* __restrict__ sums_part, const float* __restrict__ cntbuf,
    const int* __restrict__ valid, float* __restrict__ out) {
    int bn = blockIdx.x;       // 64
    int b = bn >> 4, n = bn & 15;
    int tid = threadIdx.x;
    int slot = tid & 15, cg = tid >> 4;
    int lane = tid & 63, wave = tid >> 6;

    __shared__ float red2[4][17];
    __shared__ float fin[16];

    float sv = 0.f;
    const float* src = sums_part + (size_t)b * NCC * 256 + n * 16 + slot;
    for (int k = 0; k < 25; ++k) sv += src[(size_t)(cg + 16 * k) * 256];
    sv += __shfl_xor(sv, 16);
    sv += __shfl_xor(sv, 32);
    if (lane < 16) red2[wave][lane] = sv;
    __syncthreads();
    if (tid < 16) fin[tid] = red2[0][tid] + red2[1][tid] + red2[2][tid] + red2[3][tid];
    __syncthreads();

    if (tid == 0) {
        float vw = (float)valid[bn];
        float cnt = cntbuf[bn];
        float mloss = 0.f, iloss = 0.f;
#pragma unroll
        for (int r = 0; r < 8; ++r) {
            float p2 = fin[r * 2];
            float tp = fin[r * 2 + 1];
            float denom = fmaxf(p2 + cnt, 1e-8f);
            float dice = 1.f - 2.f * tp / denom;
            if (r == 0) mloss = dice * vw;
            else iloss += dice * vw;
        }
        atomicAdd(out + 0, mloss);
        atomicAdd(out + 1, iloss);
    }
}

extern "C" void kernel_launch(void* const* d_in, const int* in_sizes, int n_in,
                              void* d_out, int out_size, void* d_ws, size_t ws_size,
                              hipStream_t stream) {
    const float* pred = (const float*)d_in[0];
    const float* feat = (const float*)d_in[1];
    const float* gtin = (const float*)d_in[2];
    const int* valid  = (const int*)d_in[3];
    float* out = (float*)d_out;

    char* ws = (char*)d_ws;
    float* ms_part   = (float*)(ws);                 // 800*512*4   = 1,638,400
    float* s2_part   = (float*)(ws + 1638400);       // 800*16*4    =    51,200
    float* cand_val  = (float*)(ws + 1689600);       // 64*175*4    =    44,800
    int*   cand_idx  = (int*)  (ws + 1734400);       //                  44,800
    float* sums_part = (float*)(ws + 1779200);       // 1600*256*4  = 1,638,400
    float* Ebuf      = (float*)(ws + 3417600);       // 64*256*4    =    65,536
    float* cntbuf    = (float*)(ws + 3483136);       // 256

    hipMemsetAsync(out, 0, 3 * sizeof(float), stream);
    hipMemsetAsync(cntbuf, 0, 256, stream);

    kTop<<<B * N * NSL, 256, 0, stream>>>(pred, gtin, cand_val, cand_idx, cntbuf);
    kA<<<B * NCA, 256, 0, stream>>>(feat, gtin, ms_part, s2_part);
    kB<<<B * N, 256, 0, stream>>>(feat, ms_part, s2_part, cand_val, cand_idx,
                                  cntbuf, valid, Ebuf, out);
    kC<<<B * NCC, 256, 0, stream>>>(feat, gtin, Ebuf, sums_part);
    kD<<<B * N, 256, 0, stream>>>(sums_part, cntbuf, valid, out);
}

// Round 7
// 67.114 us; speedup vs baseline: 5.0791x; 1.5545x over previous
//
#include <hip/hip_runtime.h>
#include <cstdint>
#include <cstddef>

#define B 4
#define N 16
#define V 32
#define HW 25600
#define TOPK 7
#define NSLB 5      // kTop slabs of 5120 px
#define NCA 200     // kA chunks of 128 px
#define NCC 400     // kC chunks of 64 px

__device__ __forceinline__ bool better(float av, int ai, float bv, int bi) {
    return (av > bv) || (av == bv && ai < bi);
}

// ---------------- kTop: per-(bn, 5120px slab) top-7 + cnt partial (NO atomics) ----------------
__global__ __launch_bounds__(256) void kTop(
    const float* __restrict__ pred, const float* __restrict__ gt,
    float* __restrict__ cand_val, int* __restrict__ cand_idx,
    float* __restrict__ cnt_part) {
    int s = blockIdx.x;            // 64*5 = 320
    int bn = s / NSLB, sl = s % NSLB;
    int b = bn >> 4;
    int tid = threadIdx.x;
    int lane = tid & 63, wave = tid >> 6;
    int base = sl * 5120;

    const float* gtrow = gt + (size_t)bn * HW + base;
    const float* pr = pred + (size_t)b * HW + base;

    float tv[TOPK]; int ti[TOPK];
#pragma unroll
    for (int j = 0; j < TOPK; ++j) { tv[j] = -INFINITY; ti[j] = 0x7fffffff; }
    float cnt = 0.f;

#pragma unroll
    for (int it = 0; it < 5; ++it) {
        int p = it * 1024 + tid * 4;
        float4 g4 = *reinterpret_cast<const float4*>(gtrow + p);
        float4 p4 = *reinterpret_cast<const float4*>(pr + p);
        cnt += g4.x + g4.y + g4.z + g4.w;
        float ca[4] = { p4.x * g4.x, p4.y * g4.y, p4.z * g4.z, p4.w * g4.w };
#pragma unroll
        for (int j = 0; j < 4; ++j) {
            float c = ca[j]; int pi = base + p + j;
            if (better(c, pi, tv[TOPK - 1], ti[TOPK - 1])) {
                tv[TOPK - 1] = c; ti[TOPK - 1] = pi;
#pragma unroll
                for (int q = TOPK - 2; q >= 0; --q) {
                    if (better(tv[q + 1], ti[q + 1], tv[q], ti[q])) {
                        float fv = tv[q]; int fi = ti[q];
                        tv[q] = tv[q + 1]; ti[q] = ti[q + 1];
                        tv[q + 1] = fv; ti[q + 1] = fi;
                    }
                }
            }
        }
    }

    __shared__ float rwv[4];
    __shared__ int rwi[4];
    __shared__ float csum[4];

    // cnt: per-wave reduce, store partial (regular store, no atomic)
#pragma unroll
    for (int off = 32; off > 0; off >>= 1) cnt += __shfl_down(cnt, off);
    if (lane == 0) csum[wave] = cnt;
    __syncthreads();
    if (tid == 0) cnt_part[s] = csum[0] + csum[1] + csum[2] + csum[3];

    // 7 rounds of block argmax; each thread's list is sorted, head = tv[0]
    int cbase = s * TOPK;
    for (int r = 0; r < TOPK; ++r) {
        float bv = tv[0]; int bi = ti[0];
#pragma unroll
        for (int m = 1; m <= 32; m <<= 1) {
            float ov = __shfl_xor(bv, m);
            int oi = __shfl_xor(bi, m);
            if (better(ov, oi, bv, bi)) { bv = ov; bi = oi; }
        }
        if (lane == 0) { rwv[wave] = bv; rwi[wave] = bi; }
        __syncthreads();
        float fv = rwv[0]; int fi = rwi[0];
#pragma unroll
        for (int w = 1; w < 4; ++w)
            if (better(rwv[w], rwi[w], fv, fi)) { fv = rwv[w]; fi = rwi[w]; }
        if (ti[0] == fi) {   // unique px -> exactly one popper
#pragma unroll
            for (int q = 0; q < TOPK - 1; ++q) { tv[q] = tv[q + 1]; ti[q] = ti[q + 1]; }
            tv[TOPK - 1] = -INFINITY; ti[TOPK - 1] = 0x7fffffff;
        }
        if (tid == 0) { cand_val[cbase + r] = fv; cand_idx[cbase + r] = fi; }
        __syncthreads();
    }
}

// ---------------- kA: ms[n][v] + s2[n] partials per (b, 128px chunk) ----------------
__global__ __launch_bounds__(256) void kA(
    const float* __restrict__ feat, const float* __restrict__ gt,
    float* __restrict__ ms_part, float* __restrict__ s2_part) {
    int s = blockIdx.x;                 // 800
    int xcd = s & 7;
    int b = xcd >> 1;
    int ch = (s >> 3) * 2 + (xcd & 1);  // 0..199
    int c0 = ch * 128;
    int tid = threadIdx.x;
    int ng = tid >> 6, vg = (tid >> 3) & 7, pg = tid & 7;

    const float* gb = gt + (size_t)(b * N + ng * 4) * HW + c0 + pg * 4;
    const float* fb = feat + (size_t)(b * V + vg * 4) * HW + c0 + pg * 4;

    float acc[4][4];
#pragma unroll
    for (int i = 0; i < 4; ++i)
#pragma unroll
        for (int j = 0; j < 4; ++j) acc[i][j] = 0.f;
    float s2a[4] = { 0.f, 0.f, 0.f, 0.f };

#pragma unroll
    for (int q = 0; q < 4; ++q) {
        int p = q * 32;
        float4 g4[4], f4[4];
#pragma unroll
        for (int i = 0; i < 4; ++i)
            g4[i] = *reinterpret_cast<const float4*>(gb + (size_t)i * HW + p);
#pragma unroll
        for (int j = 0; j < 4; ++j)
            f4[j] = *reinterpret_cast<const float4*>(fb + (size_t)j * HW + p);
        float ffx = 0.f, ffy = 0.f, ffz = 0.f, ffw = 0.f;
#pragma unroll
        for (int j = 0; j < 4; ++j) {
            ffx = fmaf(f4[j].x, f4[j].x, ffx);
            ffy = fmaf(f4[j].y, f4[j].y, ffy);
            ffz = fmaf(f4[j].z, f4[j].z, ffz);
            ffw = fmaf(f4[j].w, f4[j].w, ffw);
        }
#pragma unroll
        for (int i = 0; i < 4; ++i) {
#pragma unroll
            for (int j = 0; j < 4; ++j) {
                acc[i][j] = fmaf(g4[i].x, f4[j].x, acc[i][j]);
                acc[i][j] = fmaf(g4[i].y, f4[j].y, acc[i][j]);
                acc[i][j] = fmaf(g4[i].z, f4[j].z, acc[i][j]);
                acc[i][j] = fmaf(g4[i].w, f4[j].w, acc[i][j]);
            }
            s2a[i] = fmaf(g4[i].x, ffx, s2a[i]);
            s2a[i] = fmaf(g4[i].y, ffy, s2a[i]);
            s2a[i] = fmaf(g4[i].z, ffz, s2a[i]);
            s2a[i] = fmaf(g4[i].w, ffw, s2a[i]);
        }
    }
#pragma unroll
    for (int m = 1; m <= 4; m <<= 1)
#pragma unroll
        for (int i = 0; i < 4; ++i)
#pragma unroll
            for (int j = 0; j < 4; ++j) acc[i][j] += __shfl_xor(acc[i][j], m);
    size_t blk = (size_t)(b * NCA + ch);
    if (pg == 0) {
        float* dst = ms_part + blk * 512;
#pragma unroll
        for (int i = 0; i < 4; ++i)
#pragma unroll
            for (int j = 0; j < 4; ++j)
                dst[(ng * 4 + i) * 32 + vg * 4 + j] = acc[i][j];
    }
#pragma unroll
    for (int m = 1; m <= 32; m <<= 1)
#pragma unroll
        for (int i = 0; i < 4; ++i) s2a[i] += __shfl_xor(s2a[i], m);
    if ((tid & 63) == 0) {
#pragma unroll
        for (int i = 0; i < 4; ++i)
            s2_part[blk * 16 + ng * 4 + i] = s2a[i];
    }
}

// ---------------- kB: merge candidates, cnt, mu, E, l2 loss ----------------
__global__ __launch_bounds__(256) void kB(
    const float* __restrict__ feat, const float* __restrict__ ms_part,
    const float* __restrict__ s2_part,
    const float* __restrict__ cand_val, const int* __restrict__ cand_idx,
    const float* __restrict__ cnt_part, const int* __restrict__ valid,
    float* __restrict__ Ebuf, float* __restrict__ cntbuf, float* __restrict__ out) {
    int bn = blockIdx.x;
    int b = bn >> 4, n = bn & 15;
    int tid = threadIdx.x;
    int lane = tid & 63, wave = tid >> 6;

    __shared__ int idx7[TOPK];
    __shared__ float msred[2][32];
    __shared__ float s2sh;

    if (wave == 0) {
        // merge NSLB*7 = 35 candidates: lane < 35 holds one
        float cv = -INFINITY; int ci = 0x7fffffff;
        if (lane < NSLB * TOPK) {
            cv = cand_val[(size_t)bn * NSLB * TOPK + lane];
            ci = cand_idx[(size_t)bn * NSLB * TOPK + lane];
        }
#pragma unroll
        for (int r = 0; r < TOPK; ++r) {
            float bv = cv; int bi = ci;
#pragma unroll
            for (int m = 1; m <= 32; m <<= 1) {
                float ov = __shfl_xor(bv, m);
                int oi = __shfl_xor(bi, m);
                if (better(ov, oi, bv, bi)) { bv = ov; bi = oi; }
            }
            if (ci == bi) { cv = -INFINITY; ci = 0x7fffffff; }
            if (lane == 0) idx7[r] = bi;
        }
    } else if (wave <= 2) {
        int half = wave - 1;
        int v = lane & 31, hh = lane >> 5;
        int cstart = half * 100 + hh * 50;
        const float* src = ms_part + (size_t)b * NCA * 512 + n * 32 + v;
        float sm = 0.f;
        for (int k = 0; k < 50; ++k) sm += src[(size_t)(cstart + k) * 512];
        sm += __shfl_xor(sm, 32);
        if (lane < 32) msred[half][v] = sm;
    } else {
        float sv = 0.f;
        const float* src = s2_part + (size_t)b * NCA * 16 + n;
        for (int k = lane; k < NCA; k += 64) sv += src[(size_t)k * 16];
#pragma unroll
        for (int m = 1; m <= 32; m <<= 1) sv += __shfl_xor(sv, m);
        if (lane == 0) s2sh = sv;
    }
    __syncthreads();

    if (tid < 32) {
        const float* cp = cnt_part + bn * NSLB;
        float cnt = cp[0] + cp[1] + cp[2] + cp[3] + cp[4];
        float msum = msred[0][tid] + msred[1][tid];
        float pix = fmaxf(cnt, 1.0f);
        float mu = msum / pix;
        Ebuf[(size_t)bn * 256 + tid] = mu;
        float msq = mu * mu;
#pragma unroll
        for (int m = 1; m <= 16; m <<= 1) msq += __shfl_xor(msq, m);
        if (tid == 0) {
            cntbuf[bn] = cnt;
            float l2 = (s2sh / pix - msq) * (float)valid[bn];
            atomicAdd(out + 2, l2);
        }
    } else {
        int t = tid - 32;
        if (t < 224) {
            int r = t >> 5, v = t & 31;
            Ebuf[(size_t)bn * 256 + (r + 1) * 32 + v] =
                feat[((size_t)b * V + v) * HW + idx7[r]];
        }
    }
}

// ---------------- kC: sigmoid-GEMM dice partials per (b, 64px chunk) ----------------
__global__ __launch_bounds__(256) void kC(
    const float* __restrict__ feat, const float* __restrict__ gt,
    const float* __restrict__ Ebuf, float* __restrict__ sums_part) {
    int s = blockIdx.x;                 // 1600
    int xcd = s & 7;
    int b = xcd >> 1;
    int ch = (s >> 3) * 2 + (xcd & 1);  // 0..399
    int c0 = ch * 64;
    int tid = threadIdx.x;
    int n = tid >> 4, pg = tid & 15;

    __shared__ float e_lds[8 * 16 * 36];
    __shared__ float red[16][17];

    const float* eb = Ebuf + (size_t)b * 4096;
#pragma unroll
    for (int k = 0; k < 16; ++k) {
        int q = tid + 256 * k;
        int nn = q >> 8, rr = (q >> 5) & 7, vv = q & 31;
        e_lds[(rr * 16 + nn) * 36 + vv] = eb[q];
    }
    __syncthreads();

    const float* fb = feat + (size_t)b * V * HW + c0 + pg * 4;
    float4 g4 = *reinterpret_cast<const float4*>(gt + (size_t)(b * N + n) * HW + c0 + pg * 4);

    float acc[8][4];
#pragma unroll
    for (int r = 0; r < 8; ++r)
#pragma unroll
        for (int j = 0; j < 4; ++j) acc[r][j] = 0.f;

    float4 c0_ = *reinterpret_cast<const float4*>(fb);
    float4 c1_ = *reinterpret_cast<const float4*>(fb + HW);
    float4 c2_ = *reinterpret_cast<const float4*>(fb + 2 * (size_t)HW);
    float4 c3_ = *reinterpret_cast<const float4*>(fb + 3 * (size_t)HW);
#pragma unroll
    for (int vq = 0; vq < 8; ++vq) {
        float4 n0_, n1_, n2_, n3_;
        if (vq < 7) {
            const float* np = fb + (size_t)(vq * 4 + 4) * HW;
            n0_ = *reinterpret_cast<const float4*>(np);
            n1_ = *reinterpret_cast<const float4*>(np + HW);
            n2_ = *reinterpret_cast<const float4*>(np + 2 * (size_t)HW);
            n3_ = *reinterpret_cast<const float4*>(np + 3 * (size_t)HW);
        }
#pragma unroll
        for (int r = 0; r < 8; ++r) {
            float4 e4 = *reinterpret_cast<const float4*>(&e_lds[(r * 16 + n) * 36 + vq * 4]);
            acc[r][0] = fmaf(e4.x, c0_.x, acc[r][0]);
            acc[r][0] = fmaf(e4.y, c1_.x, acc[r][0]);
            acc[r][0] = fmaf(e4.z, c2_.x, acc[r][0]);
            acc[r][0] = fmaf(e4.w, c3_.x, acc[r][0]);
            acc[r][1] = fmaf(e4.x, c0_.y, acc[r][1]);
            acc[r][1] = fmaf(e4.y, c1_.y, acc[r][1]);
            acc[r][1] = fmaf(e4.z, c2_.y, acc[r][1]);
            acc[r][1] = fmaf(e4.w, c3_.y, acc[r][1]);
            acc[r][2] = fmaf(e4.x, c0_.z, acc[r][2]);
            acc[r][2] = fmaf(e4.y, c1_.z, acc[r][2]);
            acc[r][2] = fmaf(e4.z, c2_.z, acc[r][2]);
            acc[r][2] = fmaf(e4.w, c3_.z, acc[r][2]);
            acc[r][3] = fmaf(e4.x, c0_.w, acc[r][3]);
            acc[r][3] = fmaf(e4.y, c1_.w, acc[r][3]);
            acc[r][3] = fmaf(e4.z, c2_.w, acc[r][3]);
            acc[r][3] = fmaf(e4.w, c3_.w, acc[r][3]);
        }
        if (vq < 7) { c0_ = n0_; c1_ = n1_; c2_ = n2_; c3_ = n3_; }
    }

    float p2[8], tp[8];
#pragma unroll
    for (int r = 0; r < 8; ++r) { p2[r] = 0.f; tp[r] = 0.f; }
    float ga[4] = { g4.x, g4.y, g4.z, g4.w };
#pragma unroll
    for (int r = 0; r < 8; ++r)
#pragma unroll
        for (int j = 0; j < 4; ++j) {
            float sg = 1.f / (1.f + __expf(-acc[r][j]));
            p2[r] = fmaf(sg, sg, p2[r]);
            tp[r] = fmaf(ga[j], sg, tp[r]);
        }
#pragma unroll
    for (int m = 1; m <= 8; m <<= 1)
#pragma unroll
        for (int r = 0; r < 8; ++r) {
            p2[r] += __shfl_xor(p2[r], m);
            tp[r] += __shfl_xor(tp[r], m);
        }
    if (pg == 0) {
#pragma unroll
        for (int r = 0; r < 8; ++r) {
            red[n][r * 2] = p2[r];
            red[n][r * 2 + 1] = tp[r];
        }
    }
    __syncthreads();
    sums_part[(size_t)(b * NCC + ch) * 256 + tid] = red[tid >> 4][tid & 15];
}

// ---------------- kD: reduce dice partials, fold dice losses ----------------
__global__ __launch_bounds__(256) void kD(
    const float* __restrict__ sums_part, const float* __restrict__ cntbuf,
    const int* __restrict__ valid, float* __restrict__ out) {
    int bn = blockIdx.x;       // 64
    int b = bn >> 4, n = bn & 15;
    int tid = threadIdx.x;
    int slot = tid & 15, cg = tid >> 4;
    int lane = tid & 63, wave = tid >> 6;

    __shared__ float red2[4][17];
    __shared__ float fin[16];

    float sv = 0.f;
    const float* src = sums_part + (size_t)b * NCC * 256 + n * 16 + slot;
    for (int k = 0; k < 25; ++k) sv += src[(size_t)(cg + 16 * k) * 256];
    sv += __shfl_xor(sv, 16);
    sv += __shfl_xor(sv, 32);
    if (lane < 16) red2[wave][lane] = sv;
    __syncthreads();
    if (tid < 16) fin[tid] = red2[0][tid] + red2[1][tid] + red2[2][tid] + red2[3][tid];
    __syncthreads();

    if (tid == 0) {
        float vw = (float)valid[bn];
        float cnt = cntbuf[bn];
        float mloss = 0.f, iloss = 0.f;
#pragma unroll
        for (int r = 0; r < 8; ++r) {
            float p2 = fin[r * 2];
            float tp = fin[r * 2 + 1];
            float denom = fmaxf(p2 + cnt, 1e-8f);
            float dice = 1.f - 2.f * tp / denom;
            if (r == 0) mloss = dice * vw;
            else iloss += dice * vw;
        }
        atomicAdd(out + 0, mloss);
        atomicAdd(out + 1, iloss);
    }
}

extern "C" void kernel_launch(void* const* d_in, const int* in_sizes, int n_in,
                              void* d_out, int out_size, void* d_ws, size_t ws_size,
                              hipStream_t stream) {
    const float* pred = (const float*)d_in[0];
    const float* feat = (const float*)d_in[1];
    const float* gtin = (const float*)d_in[2];
    const int* valid  = (const int*)d_in[3];
    float* out = (float*)d_out;

    char* ws = (char*)d_ws;
    float* ms_part   = (float*)(ws);                 // 800*512*4   = 1,638,400
    float* s2_part   = (float*)(ws + 1638400);       // 800*16*4    =    51,200
    float* cand_val  = (float*)(ws + 1689600);       // 320*7*4     =     8,960
    int*   cand_idx  = (int*)  (ws + 1698560);       //                   8,960
    float* cnt_part  = (float*)(ws + 1707520);       // 320*4       =     1,280
    float* sums_part = (float*)(ws + 1708800);       // 1600*256*4  = 1,638,400
    float* Ebuf      = (float*)(ws + 3347200);       // 64*256*4    =    65,536
    float* cntbuf    = (float*)(ws + 3412736);       // 256

    hipMemsetAsync(out, 0, 3 * sizeof(float), stream);

    kTop<<<B * N * NSLB, 256, 0, stream>>>(pred, gtin, cand_val, cand_idx, cnt_part);
    kA<<<B * NCA, 256, 0, stream>>>(feat, gtin, ms_part, s2_part);
    kB<<<B * N, 256, 0, stream>>>(feat, ms_part, s2_part, cand_val, cand_idx,
                                  cnt_part, valid, Ebuf, cntbuf, out);
    kC<<<B * NCC, 256, 0, stream>>>(feat, gtin, Ebuf, sums_part);
    kD<<<B * N, 256, 0, stream>>>(sums_part, cntbuf, valid, out);
}